// Round 1
// baseline (436.679 us; speedup 1.0000x reference)
//
#include <hip/hip_runtime.h>
#include <cfloat>

// Shapes (fixed by the problem): x = [32, 1, 8192, 256] fp32
// out = [32, 1, 4096, 256] fp32
#define BATCH     32
#define H_IN      8192
#define H_OUT     4096
#define W         256
#define W4        64        // W as float4
#define CH        32        // output rows per thread
#define BLK_PER_B 32        // blocks per batch (32*128 rows = 4096)

typedef float f32x4 __attribute__((ext_vector_type(4)));

__device__ __forceinline__ float4 max3_f4(float4 a, float4 b, float4 c) {
    float4 m;
    m.x = fmaxf(a.x, fmaxf(b.x, c.x));
    m.y = fmaxf(a.y, fmaxf(b.y, c.y));
    m.z = fmaxf(a.z, fmaxf(b.z, c.z));
    m.w = fmaxf(a.w, fmaxf(b.w, c.w));
    return m;
}

// Kernel 1: streaming pooled min/max partials ONLY — no pooled store.
// Reads all of x (256 MiB) -> leaves it resident in the 256 MiB Infinity Cache.
// Grid: BATCH * BLK_PER_B = 1024 blocks, 256 threads.
__global__ __launch_bounds__(256) void pool_minmax(
        const float* __restrict__ x,
        float* __restrict__ partial_min, float* __restrict__ partial_max) {
    const int batch = blockIdx.x >> 5;          // / BLK_PER_B
    const int blk   = blockIdx.x & 31;
    const int tid   = threadIdx.x;
    const int w4    = tid & 63;
    const int rg    = tid >> 6;                 // wave index, 0..3
    const int h0    = blk * (BLK_PER_B * 4) + rg * CH;

    const float4* xin = (const float4*)x + (size_t)batch * H_IN * W4 + w4;

    float lmin = FLT_MAX, lmax = -FLT_MAX;

    float4 prev;
    const int r0 = 2 * h0 - 1;
    if (r0 >= 0) prev = xin[(size_t)r0 * W4];
    else         prev = make_float4(-FLT_MAX, -FLT_MAX, -FLT_MAX, -FLT_MAX);

    #pragma unroll 4
    for (int i = 0; i < CH; ++i) {
        const int r = 2 * (h0 + i);
        float4 a = xin[(size_t)r * W4];
        float4 c = xin[(size_t)(r + 1) * W4];
        float4 m = max3_f4(prev, a, c);
        prev = c;
        lmax = fmaxf(lmax, fmaxf(fmaxf(m.x, m.y), fmaxf(m.z, m.w)));
        lmin = fminf(lmin, fminf(fminf(m.x, m.y), fminf(m.z, m.w)));
    }

    // wave reduce (64 lanes)
    #pragma unroll
    for (int off = 32; off > 0; off >>= 1) {
        lmax = fmaxf(lmax, __shfl_down(lmax, off, 64));
        lmin = fminf(lmin, __shfl_down(lmin, off, 64));
    }
    __shared__ float smax[4], smin[4];
    if ((tid & 63) == 0) { smax[rg] = lmax; smin[rg] = lmin; }
    __syncthreads();
    if (tid == 0) {
        float bmax = smax[0], bmin = smin[0];
        #pragma unroll
        for (int i = 1; i < 4; ++i) {
            bmax = fmaxf(bmax, smax[i]);
            bmin = fminf(bmin, smin[i]);
        }
        partial_max[blockIdx.x] = bmax;
        partial_min[blockIdx.x] = bmin;
    }
}

// Kernel 2: fused stats-reduce + pool-recompute + normalize.
// Re-reads x (L3-resident from kernel 1), writes out once with nontemporal
// stores so the output stream doesn't evict x from L3.
// Grid: BATCH * BLK_PER_B = 1024 blocks, 256 threads.
__global__ __launch_bounds__(256) void pool_normalize(
        const float* __restrict__ x, float* __restrict__ out,
        const float* __restrict__ pmin, const float* __restrict__ pmax) {
    const int batch = blockIdx.x >> 5;
    const int blk   = blockIdx.x & 31;
    const int tid   = threadIdx.x;

    // Per-block reduction of this batch's 32 partials (2 KB, L2-hit).
    __shared__ float s_mn, s_inv;
    if (tid < 64) {
        float mn = (tid < BLK_PER_B) ? pmin[batch * BLK_PER_B + tid] : FLT_MAX;
        float mx = (tid < BLK_PER_B) ? pmax[batch * BLK_PER_B + tid] : -FLT_MAX;
        #pragma unroll
        for (int off = 16; off > 0; off >>= 1) {
            mn = fminf(mn, __shfl_down(mn, off, 64));
            mx = fmaxf(mx, __shfl_down(mx, off, 64));
        }
        if (tid == 0) { s_mn = mn; s_inv = 1.0f / (mx - mn); }
    }
    __syncthreads();
    const float mn  = s_mn;
    const float inv = s_inv;

    const int w4 = tid & 63;
    const int rg = tid >> 6;
    const int h0 = blk * (BLK_PER_B * 4) + rg * CH;

    const float4* xin = (const float4*)x + (size_t)batch * H_IN * W4 + w4;
    f32x4*        po  = (f32x4*)out + ((size_t)batch * H_OUT + h0) * W4 + w4;

    float4 prev;
    const int r0 = 2 * h0 - 1;
    if (r0 >= 0) prev = xin[(size_t)r0 * W4];
    else         prev = make_float4(-FLT_MAX, -FLT_MAX, -FLT_MAX, -FLT_MAX);

    #pragma unroll 4
    for (int i = 0; i < CH; ++i) {
        const int r = 2 * (h0 + i);
        float4 a = xin[(size_t)r * W4];
        float4 c = xin[(size_t)(r + 1) * W4];
        float4 m = max3_f4(prev, a, c);
        prev = c;
        f32x4 v = { (m.x - mn) * inv,
                    (m.y - mn) * inv,
                    (m.z - mn) * inv,
                    (m.w - mn) * inv };
        __builtin_nontemporal_store(v, po + (size_t)i * W4);
    }
}

extern "C" void kernel_launch(void* const* d_in, const int* in_sizes, int n_in,
                              void* d_out, int out_size, void* d_ws, size_t ws_size,
                              hipStream_t stream) {
    const float* x   = (const float*)d_in[0];
    float*       out = (float*)d_out;
    float*       ws  = (float*)d_ws;

    float* pmin = ws;                  // 1024 floats
    float* pmax = ws + 1024;           // 1024 floats

    pool_minmax<<<BATCH * BLK_PER_B, 256, 0, stream>>>(x, pmin, pmax);
    pool_normalize<<<BATCH * BLK_PER_B, 256, 0, stream>>>(x, out, pmin, pmax);
}

// Round 2
// 427.103 us; speedup vs baseline: 1.0224x; 1.0224x over previous
//
#include <hip/hip_runtime.h>
#include <cfloat>

// Shapes (fixed): x = [32, 1, 8192, 256] fp32, out = [32, 1, 4096, 256] fp32
#define BATCH     32
#define H_IN      8192
#define H_OUT     4096
#define W         256
#define W4        64        // W as float4
#define CH        16        // output rows per thread in kernel 1
#define BLK_PER_B 64        // blocks per batch (64 blocks * 64 rows = 4096)

typedef float f32x4 __attribute__((ext_vector_type(4)));

__device__ __forceinline__ float4 max3_f4(float4 a, float4 b, float4 c) {
    float4 m;
    m.x = fmaxf(a.x, fmaxf(b.x, c.x));
    m.y = fmaxf(a.y, fmaxf(b.y, c.y));
    m.z = fmaxf(a.z, fmaxf(b.z, c.z));
    m.w = fmaxf(a.w, fmaxf(b.w, c.w));
    return m;
}

// Kernel 1: maxpool along H -> write UNSCALED pooled to out (normal stores:
// we want these 128 MiB resident in L3 for kernel 2's re-read) + per-block
// min/max partials. Grid: BATCH*BLK_PER_B = 2048 blocks, 256 threads
// (8 blocks/CU, full 32 waves/CU).
__global__ __launch_bounds__(256) void pool_store_partial(
        const float* __restrict__ x, float* __restrict__ out,
        float* __restrict__ partial_min, float* __restrict__ partial_max) {
    const int batch = blockIdx.x >> 6;          // / BLK_PER_B
    const int blk   = blockIdx.x & 63;
    const int tid   = threadIdx.x;
    const int w4    = tid & 63;
    const int rg    = tid >> 6;                 // wave index, 0..3
    const int h0    = blk * (4 * CH) + rg * CH; // blk*64 + rg*16

    const float4* xin = (const float4*)x + (size_t)batch * H_IN * W4 + w4;
    float4*       po  = (float4*)out + ((size_t)batch * H_OUT + h0) * W4 + w4;

    float lmin = FLT_MAX, lmax = -FLT_MAX;

    float4 prev;
    const int r0 = 2 * h0 - 1;
    if (r0 >= 0) prev = xin[(size_t)r0 * W4];
    else         prev = make_float4(-FLT_MAX, -FLT_MAX, -FLT_MAX, -FLT_MAX);

    #pragma unroll 4
    for (int i = 0; i < CH; ++i) {
        const int r = 2 * (h0 + i);
        float4 a = xin[(size_t)r * W4];
        float4 c = xin[(size_t)(r + 1) * W4];
        float4 m = max3_f4(prev, a, c);
        po[(size_t)i * W4] = m;
        prev = c;
        lmax = fmaxf(lmax, fmaxf(fmaxf(m.x, m.y), fmaxf(m.z, m.w)));
        lmin = fminf(lmin, fminf(fminf(m.x, m.y), fminf(m.z, m.w)));
    }

    // wave reduce (64 lanes)
    #pragma unroll
    for (int off = 32; off > 0; off >>= 1) {
        lmax = fmaxf(lmax, __shfl_down(lmax, off, 64));
        lmin = fminf(lmin, __shfl_down(lmin, off, 64));
    }
    __shared__ float smax[4], smin[4];
    if ((tid & 63) == 0) { smax[rg] = lmax; smin[rg] = lmin; }
    __syncthreads();
    if (tid == 0) {
        float bmax = smax[0], bmin = smin[0];
        #pragma unroll
        for (int i = 1; i < 4; ++i) {
            bmax = fmaxf(bmax, smax[i]);
            bmin = fminf(bmin, smin[i]);
        }
        partial_max[blockIdx.x] = bmax;
        partial_min[blockIdx.x] = bmin;
    }
}

// Kernel 2: fused stats-reduce + in-place rescale of out.
// Each block reduces its batch's 64 partials (L2-hit, 512 B), then rescales
// a contiguous 64-row slice of out. Re-read is L3-hot (128 MiB intermediate,
// freshly written, fits the 256 MiB Infinity Cache with headroom); final
// writes are nontemporal (never reused).
// Grid: BATCH*BLK_PER_B = 2048 blocks, 256 threads.
__global__ __launch_bounds__(256) void finish_normalize(
        float* __restrict__ out,
        const float* __restrict__ pmin, const float* __restrict__ pmax) {
    const int batch = blockIdx.x >> 6;
    const int blk   = blockIdx.x & 63;
    const int tid   = threadIdx.x;

    __shared__ float s_mn, s_inv;
    if (tid < 64) {
        float mn = pmin[batch * BLK_PER_B + tid];
        float mx = pmax[batch * BLK_PER_B + tid];
        #pragma unroll
        for (int off = 32; off > 0; off >>= 1) {
            mn = fminf(mn, __shfl_down(mn, off, 64));
            mx = fmaxf(mx, __shfl_down(mx, off, 64));
        }
        if (tid == 0) { s_mn = mn; s_inv = 1.0f / (mx - mn); }
    }
    __syncthreads();
    const float mn  = s_mn;
    const float inv = s_inv;

    // Block slice: 64 rows * 64 float4 = 4096 float4 (64 KiB), contiguous.
    f32x4* p = (f32x4*)out + (size_t)batch * (H_OUT * W4) + (size_t)blk * 4096;
    #pragma unroll 4
    for (int j = 0; j < 16; ++j) {
        const int idx = tid + j * 256;
        f32x4 v = p[idx];
        v.x = (v.x - mn) * inv;
        v.y = (v.y - mn) * inv;
        v.z = (v.z - mn) * inv;
        v.w = (v.w - mn) * inv;
        __builtin_nontemporal_store(v, p + idx);
    }
}

extern "C" void kernel_launch(void* const* d_in, const int* in_sizes, int n_in,
                              void* d_out, int out_size, void* d_ws, size_t ws_size,
                              hipStream_t stream) {
    const float* x   = (const float*)d_in[0];
    float*       out = (float*)d_out;
    float*       ws  = (float*)d_ws;

    float* pmin = ws;                  // 2048 floats
    float* pmax = ws + 2048;           // 2048 floats

    pool_store_partial<<<BATCH * BLK_PER_B, 256, 0, stream>>>(x, out, pmin, pmax);
    finish_normalize<<<BATCH * BLK_PER_B, 256, 0, stream>>>(out, pmin, pmax);
}